// Round 5
// baseline (265.950 us; speedup 1.0000x reference)
//
#include <hip/hip_runtime.h>
#include <hip/hip_bf16.h>
#include <math.h>

#define S_LEN 2048
#define D_KV  64
#define BQ    128   // q rows per block = 4 q-subtiles x 32 (x2 k-splits)
#define BK    64
#define LP    72    // LDS row stride (bf16 elems): %8==0 for aligned b128
#define HALF_S (S_LEN / 2)
#define KV_SHORTS (64 * LP)

typedef __attribute__((ext_vector_type(8)))  short    bh8;    // 8 bf16 (A/B frag)
typedef __attribute__((ext_vector_type(4)))  short    sh4;
typedef __attribute__((ext_vector_type(4)))  unsigned ux4;
typedef __attribute__((ext_vector_type(16))) float    f32x16; // 32x32 C/D frag

__device__ __forceinline__ short f2bf(float f) {
    unsigned u = __builtin_bit_cast(unsigned, f);
    u += 0x7fffu + ((u >> 16) & 1u);   // RNE
    return (short)(u >> 16);
}
__device__ __forceinline__ unsigned pk2(float a, float b) {
    return (unsigned)(unsigned short)f2bf(a) |
           ((unsigned)(unsigned short)f2bf(b) << 16);
}

__global__ __launch_bounds__(512, 4)
void attn_fwd(const float* __restrict__ Qg, const float* __restrict__ Kg,
              const float* __restrict__ Vg, const float* __restrict__ Mg,
              float* __restrict__ Og)
{
    // smem: [split0: K | V][split1: K | V]  = 36864 B; reused as fp32 merge buffer
    __shared__ __align__(16) short smem[4 * KV_SHORTS];

    const int tid   = threadIdx.x;
    const int wave  = tid >> 6;
    const int lane  = tid & 63;
    const int n     = lane & 31;   // C/D col (= q within subtile)
    const int hi    = lane >> 5;   // half-wave 0/1
    const int split = wave >> 2;   // key-range split 0/1
    const int qsub  = wave & 3;    // q subtile within block
    const int gtid  = tid & 255;   // thread id within split group

    const int qt = blockIdx.x;
    const int bh = blockIdx.y;
    const int b  = bh >> 4;

    const int qw = qt * BQ + qsub * 32;

    short* k_lds = smem + split * 2 * KV_SHORTS;
    short* v_lds = k_lds + KV_SHORTS;

    const float* Qp = Qg + ((size_t)bh * S_LEN + qw) * D_KV;
    const float* Kp = Kg + (size_t)bh * S_LEN * D_KV;
    const float* Vp = Vg + (size_t)bh * S_LEN * D_KV;
    const float* Mp = Mg + (size_t)b * S_LEN * S_LEN;
    float*       Op = Og + ((size_t)bh * S_LEN + qw) * D_KV;

    // ---- Q^T B-frags: B[k = d = kc*16+hi*8+j][col = q = n], scale 1/8 folded ----
    bh8 qf[4];
#pragma unroll
    for (int kc = 0; kc < 4; ++kc) {
        const float* src = Qp + n * D_KV + kc * 16 + hi * 8;
        float4 a0 = *(const float4*)(src);
        float4 a1 = *(const float4*)(src + 4);
        bh8 f;
        f[0] = f2bf(a0.x * 0.125f); f[1] = f2bf(a0.y * 0.125f);
        f[2] = f2bf(a0.z * 0.125f); f[3] = f2bf(a0.w * 0.125f);
        f[4] = f2bf(a1.x * 0.125f); f[5] = f2bf(a1.y * 0.125f);
        f[6] = f2bf(a1.z * 0.125f); f[7] = f2bf(a1.w * 0.125f);
        qf[kc] = f;
    }

    f32x16 o0, o1;      // O^T accumulators: rows d = rowo+4hi (+32), col q = n
    float  l = 0.f;     // per-lane partial sum of column q = n
#pragma unroll
    for (int i = 0; i < 16; ++i) { o0[i] = 0.f; o1[i] = 0.f; }

    const int kt0 = split * HALF_S;
    for (int it = 0; it < HALF_S / BK; ++it) {
        const int kt = kt0 + it * BK;
        // ---- stage K tile (this split's 256 threads) ----
#pragma unroll
        for (int i = 0; i < 4; ++i) {
            int idx = gtid + 256 * i;
            int kr  = idx >> 4;
            int db  = (idx & 15) * 4;
            float4 kv = *(const float4*)(Kp + (size_t)(kt + kr) * D_KV + db);
            sh4 s4;
            s4[0] = f2bf(kv.x); s4[1] = f2bf(kv.y);
            s4[2] = f2bf(kv.z); s4[3] = f2bf(kv.w);
            *(sh4*)&k_lds[kr * LP + db] = s4;
        }
        // ---- stage V transposed: group-wave qsub covers d-cols [qsub*16,+16) ----
        {
            int kr = lane;
#pragma unroll
            for (int i = 0; i < 4; ++i) {
                int db = qsub * 16 + i * 4;
                float4 vv = *(const float4*)(Vp + (size_t)(kt + kr) * D_KV + db);
                v_lds[(db + 0) * LP + kr] = f2bf(vv.x);
                v_lds[(db + 1) * LP + kr] = f2bf(vv.y);
                v_lds[(db + 2) * LP + kr] = f2bf(vv.z);
                v_lds[(db + 3) * LP + kr] = f2bf(vv.w);
            }
        }
        __syncthreads();

        // ---- T = S^T = K * Q^T : two 32x32 tiles (keys 0-31 / 32-63) ----
        // C/D: row = key = (r&3)+8*(r>>2)+4*hi, col = q = n
        f32x16 s0, s1;
#pragma unroll
        for (int i = 0; i < 16; ++i) { s0[i] = 0.f; s1[i] = 0.f; }
#pragma unroll
        for (int kc = 0; kc < 4; ++kc) {
            int off = kc * 16 + hi * 8;
            bh8 kf0 = *(const bh8*)&k_lds[n * LP + off];
            bh8 kf1 = *(const bh8*)&k_lds[(32 + n) * LP + off];
            s0 = __builtin_amdgcn_mfma_f32_32x32x16_bf16(kf0, qf[kc], s0, 0, 0, 0);
            s1 = __builtin_amdgcn_mfma_f32_32x32x16_bf16(kf1, qf[kc], s1, 0, 0, 0);
        }

        // ---- mask + keep-positive + exp (fixed max 0) + pack to bf16 ----
        // lane reads ITS q-row of the mask: key offsets {0-3,8-11,16-19,24-27}+4hi
        unsigned pk0[8], pk1[8];
        const float* mrow = Mp + (size_t)(qw + n) * S_LEN + kt + 4 * hi;
#pragma unroll
        for (int mg = 0; mg < 4; ++mg) {
            float4 m0 = *(const float4*)(mrow + mg * 8);
            float4 m1 = *(const float4*)(mrow + 32 + mg * 8);
            float ma[4] = {m0.x, m0.y, m0.z, m0.w};
            float mb[4] = {m1.x, m1.y, m1.z, m1.w};
            float p0[4], p1[4];
#pragma unroll
            for (int x = 0; x < 4; ++x) {
                int r = 4 * mg + x;
                float t0 = s0[r] * ma[x];
                float t1 = s1[r] * mb[x];
                p0[x] = (t0 > 0.f) ? __expf(t0) : 0.f;
                p1[x] = (t1 > 0.f) ? __expf(t1) : 0.f;
                l += p0[x] + p1[x];
            }
            pk0[2 * mg]     = pk2(p0[0], p0[1]);
            pk0[2 * mg + 1] = pk2(p0[2], p0[3]);
            pk1[2 * mg]     = pk2(p1[0], p1[1]);
            pk1[2 * mg + 1] = pk2(p1[2], p1[3]);
        }

        // ---- O^T += V^T * P^T : B-frag of P^T via one xor-32 exchange ----
#pragma unroll
        for (int kc = 0; kc < 4; ++kc) {
            const unsigned* pk = (kc < 2) ? pk0 : pk1;
            int kk = kc & 1;
            unsigned X0 = hi ? pk[4 * kk]     : pk[4 * kk + 2];
            unsigned X1 = hi ? pk[4 * kk + 1] : pk[4 * kk + 3];
            unsigned Y0 = (unsigned)__shfl_xor((int)X0, 32);
            unsigned Y1 = (unsigned)__shfl_xor((int)X1, 32);
            ux4 bb;
            if (hi) { bb[0] = Y0; bb[1] = Y1; bb[2] = pk[4 * kk + 2]; bb[3] = pk[4 * kk + 3]; }
            else    { bb[0] = pk[4 * kk]; bb[1] = pk[4 * kk + 1]; bb[2] = Y0; bb[3] = Y1; }
            bh8 pb = __builtin_bit_cast(bh8, bb);
            int off = kc * 16 + hi * 8;
            bh8 vf0 = *(const bh8*)&v_lds[n * LP + off];
            bh8 vf1 = *(const bh8*)&v_lds[(32 + n) * LP + off];
            o0 = __builtin_amdgcn_mfma_f32_32x32x16_bf16(vf0, pb, o0, 0, 0, 0);
            o1 = __builtin_amdgcn_mfma_f32_32x32x16_bf16(vf1, pb, o1, 0, 0, 0);
        }
        __syncthreads();   // protect k_lds/v_lds before next staging
    }

    // ---- split-K merge through (now dead) K/V LDS: 256*33*4 = 33792 B ----
    float* fs = (float*)smem;
    if (split == 1) {
        float* dst = fs + gtid * 33;
#pragma unroll
        for (int i = 0; i < 16; ++i) { dst[i] = o0[i]; dst[16 + i] = o1[i]; }
        dst[32] = l;
    }
    __syncthreads();
    if (split == 0) {
        const float* src = fs + gtid * 33;
#pragma unroll
        for (int i = 0; i < 16; ++i) { o0[i] += src[i]; o1[i] += src[16 + i]; }
        l += src[32];
        l += __shfl_xor(l, 32);        // combine the two hi-halves of column q=n
        float inv = 1.0f / l;
        float* orow = Op + (size_t)n * D_KV;
#pragma unroll
        for (int mg = 0; mg < 4; ++mg) {
            int d0 = 8 * mg + 4 * hi;
            float4 a = {o0[4 * mg] * inv, o0[4 * mg + 1] * inv,
                        o0[4 * mg + 2] * inv, o0[4 * mg + 3] * inv};
            float4 c = {o1[4 * mg] * inv, o1[4 * mg + 1] * inv,
                        o1[4 * mg + 2] * inv, o1[4 * mg + 3] * inv};
            *(float4*)(orow + d0)      = a;
            *(float4*)(orow + 32 + d0) = c;
        }
    }
}

extern "C" void kernel_launch(void* const* d_in, const int* in_sizes, int n_in,
                              void* d_out, int out_size, void* d_ws, size_t ws_size,
                              hipStream_t stream) {
    const float* Q = (const float*)d_in[0];
    const float* K = (const float*)d_in[1];
    const float* V = (const float*)d_in[2];
    const float* M = (const float*)d_in[3];
    float*       O = (float*)d_out;
    dim3 grid(S_LEN / BQ, 32);   // 16 q-tiles x (B*H)=32
    attn_fwd<<<grid, 512, 0, stream>>>(Q, K, V, M, O);
}

// Round 6
// 204.498 us; speedup vs baseline: 1.3005x; 1.3005x over previous
//
#include <hip/hip_runtime.h>
#include <hip/hip_bf16.h>
#include <math.h>

#define S_LEN 2048
#define D_KV  64
#define BQ    128   // 4 waves x 32 q-rows
#define BK    64
#define LP    72    // LDS row stride (bf16 elems): %8==0 for aligned b128
#define NIT   (S_LEN / BK)   // 32
#define KVS   (64 * LP)      // shorts per K or V buffer

typedef __attribute__((ext_vector_type(8)))  short    bh8;    // 8 bf16 (A/B frag)
typedef __attribute__((ext_vector_type(4)))  short    sh4;
typedef __attribute__((ext_vector_type(4)))  unsigned ux4;
typedef __attribute__((ext_vector_type(16))) float    f32x16; // 32x32 C/D frag

__device__ __forceinline__ short f2bf(float f) {
    unsigned u = __builtin_bit_cast(unsigned, f);
    u += 0x7fffu + ((u >> 16) & 1u);   // RNE
    return (short)(u >> 16);
}
__device__ __forceinline__ unsigned pk2(float a, float b) {
    return (unsigned)(unsigned short)f2bf(a) |
           ((unsigned)(unsigned short)f2bf(b) << 16);
}
// barrier WITHOUT vmcnt(0) drain: in-flight global prefetches survive it.
// lgkmcnt(0) makes this wave's ds_writes visible before crossing.
__device__ __forceinline__ void lds_barrier() {
    asm volatile("s_waitcnt lgkmcnt(0)\n\ts_barrier" ::: "memory");
}

__global__ __launch_bounds__(256, 2)
void attn_fwd(const float* __restrict__ Qg, const float* __restrict__ Kg,
              const float* __restrict__ Vg, const float* __restrict__ Mg,
              float* __restrict__ Og)
{
    // [K buf0][K buf1][V buf0][V buf1] = 36864 B
    __shared__ __align__(16) short smem[4 * KVS];

    const int tid  = threadIdx.x;
    const int wave = tid >> 6;
    const int lane = tid & 63;
    const int n    = lane & 31;   // C/D col (= q within subtile)
    const int hi   = lane >> 5;   // half-wave 0/1

    const int qt = blockIdx.x;
    const int bh = blockIdx.y;
    const int b  = bh >> 4;

    const int qw = qt * BQ + wave * 32;

    const float* Qp = Qg + ((size_t)bh * S_LEN + qw) * D_KV;
    const float* Kp = Kg + (size_t)bh * S_LEN * D_KV;
    const float* Vp = Vg + (size_t)bh * S_LEN * D_KV;
    const float* Mp = Mg + (size_t)b * S_LEN * S_LEN;
    float*       Op = Og + ((size_t)bh * S_LEN + qw) * D_KV;

    // ---- Q^T B-frags: B[k = d = kc*16+hi*8+j][col = q = n], scale 1/8 folded ----
    bh8 qf[4];
#pragma unroll
    for (int kc = 0; kc < 4; ++kc) {
        const float* src = Qp + n * D_KV + kc * 16 + hi * 8;
        float4 a0 = *(const float4*)(src);
        float4 a1 = *(const float4*)(src + 4);
        bh8 f;
        f[0] = f2bf(a0.x * 0.125f); f[1] = f2bf(a0.y * 0.125f);
        f[2] = f2bf(a0.z * 0.125f); f[3] = f2bf(a0.w * 0.125f);
        f[4] = f2bf(a1.x * 0.125f); f[5] = f2bf(a1.y * 0.125f);
        f[6] = f2bf(a1.z * 0.125f); f[7] = f2bf(a1.w * 0.125f);
        qf[kc] = f;
    }

    f32x16 o0, o1;      // O^T accumulators: rows d, col q = n
    float  l = 0.f;
#pragma unroll
    for (int i = 0; i < 16; ++i) { o0[i] = 0.f; o1[i] = 0.f; }

    float4 kreg[4], vreg[4], mreg[8];   // in-flight staging registers

    auto load_kv = [&](int kt) {
#pragma unroll
        for (int i = 0; i < 4; ++i) {
            int idx = tid + 256 * i;
            int kr  = idx >> 4;
            int db  = (idx & 15) * 4;
            kreg[i] = *(const float4*)(Kp + (size_t)(kt + kr) * D_KV + db);
        }
#pragma unroll
        for (int i = 0; i < 4; ++i) {
            int db = wave * 16 + i * 4;
            vreg[i] = *(const float4*)(Vp + (size_t)(kt + lane) * D_KV + db);
        }
    };
    auto load_mask = [&](int kt) {
        const float* mrow = Mp + (size_t)(qw + n) * S_LEN + kt + 4 * hi;
#pragma unroll
        for (int mg = 0; mg < 4; ++mg) {
            mreg[2 * mg]     = *(const float4*)(mrow + mg * 8);
            mreg[2 * mg + 1] = *(const float4*)(mrow + 32 + mg * 8);
        }
    };
    auto write_stage = [&](int pb) {
        short* kl = smem + pb * KVS;
        short* vl = smem + (2 + pb) * KVS;
#pragma unroll
        for (int i = 0; i < 4; ++i) {
            int idx = tid + 256 * i;
            int kr  = idx >> 4;
            int db  = (idx & 15) * 4;
            sh4 s4;
            s4[0] = f2bf(kreg[i].x); s4[1] = f2bf(kreg[i].y);
            s4[2] = f2bf(kreg[i].z); s4[3] = f2bf(kreg[i].w);
            *(sh4*)&kl[kr * LP + db] = s4;
        }
#pragma unroll
        for (int i = 0; i < 4; ++i) {
            int db = wave * 16 + i * 4;
            vl[(db + 0) * LP + lane] = f2bf(vreg[i].x);
            vl[(db + 1) * LP + lane] = f2bf(vreg[i].y);
            vl[(db + 2) * LP + lane] = f2bf(vreg[i].z);
            vl[(db + 3) * LP + lane] = f2bf(vreg[i].w);
        }
    };

    // ---- prologue ----
    load_kv(0);
    write_stage(0);
    load_kv(BK);        // tile 1 in flight
    load_mask(0);
    lds_barrier();

    for (int j = 0; j < NIT; ++j) {
        const int pb = j & 1;
        const short* kl = smem + pb * KVS;
        const short* vl = smem + (2 + pb) * KVS;

        // ---- QK^T: T = K * Q^T, two 32x32 tiles ----
        f32x16 s0, s1;
#pragma unroll
        for (int i = 0; i < 16; ++i) { s0[i] = 0.f; s1[i] = 0.f; }
#pragma unroll
        for (int kc = 0; kc < 4; ++kc) {
            int off = kc * 16 + hi * 8;
            bh8 kf0 = *(const bh8*)&kl[n * LP + off];
            bh8 kf1 = *(const bh8*)&kl[(32 + n) * LP + off];
            s0 = __builtin_amdgcn_mfma_f32_32x32x16_bf16(kf0, qf[kc], s0, 0, 0, 0);
            s1 = __builtin_amdgcn_mfma_f32_32x32x16_bf16(kf1, qf[kc], s1, 0, 0, 0);
        }

        // ---- stage tile j+1 into the other buffer; prefetch tile j+2 ----
        if (j < NIT - 1) write_stage(pb ^ 1);
        if (j < NIT - 2) load_kv((j + 2) * BK);

        // ---- mask + keep-positive + exp (fixed max 0), then prefetch mask j+1 ----
        unsigned pk0[8], pk1[8];
#pragma unroll
        for (int mg = 0; mg < 4; ++mg) {
            float4 m0 = mreg[2 * mg];
            float4 m1 = mreg[2 * mg + 1];
            float ma[4] = {m0.x, m0.y, m0.z, m0.w};
            float mb[4] = {m1.x, m1.y, m1.z, m1.w};
            float p0[4], p1[4];
#pragma unroll
            for (int x = 0; x < 4; ++x) {
                int r = 4 * mg + x;
                float t0 = s0[r] * ma[x];
                float t1 = s1[r] * mb[x];
                p0[x] = (t0 > 0.f) ? __expf(t0) : 0.f;
                p1[x] = (t1 > 0.f) ? __expf(t1) : 0.f;
                l += p0[x] + p1[x];
            }
            pk0[2 * mg]     = pk2(p0[0], p0[1]);
            pk0[2 * mg + 1] = pk2(p0[2], p0[3]);
            pk1[2 * mg]     = pk2(p1[0], p1[1]);
            pk1[2 * mg + 1] = pk2(p1[2], p1[3]);
        }
        if (j < NIT - 1) load_mask((j + 1) * BK);

        // ---- O^T += V^T * P^T : B-frag of P^T via one xor-32 exchange ----
#pragma unroll
        for (int kc = 0; kc < 4; ++kc) {
            const unsigned* pk = (kc < 2) ? pk0 : pk1;
            int kk = kc & 1;
            unsigned X0 = hi ? pk[4 * kk]     : pk[4 * kk + 2];
            unsigned X1 = hi ? pk[4 * kk + 1] : pk[4 * kk + 3];
            unsigned Y0 = (unsigned)__shfl_xor((int)X0, 32);
            unsigned Y1 = (unsigned)__shfl_xor((int)X1, 32);
            ux4 bb;
            if (hi) { bb[0] = Y0; bb[1] = Y1; bb[2] = pk[4 * kk + 2]; bb[3] = pk[4 * kk + 3]; }
            else    { bb[0] = pk[4 * kk]; bb[1] = pk[4 * kk + 1]; bb[2] = Y0; bb[3] = Y1; }
            bh8 pb8 = __builtin_bit_cast(bh8, bb);
            int off = kc * 16 + hi * 8;
            bh8 vf0 = *(const bh8*)&vl[n * LP + off];
            bh8 vf1 = *(const bh8*)&vl[(32 + n) * LP + off];
            o0 = __builtin_amdgcn_mfma_f32_32x32x16_bf16(vf0, pb8, o0, 0, 0, 0);
            o1 = __builtin_amdgcn_mfma_f32_32x32x16_bf16(vf1, pb8, o1, 0, 0, 0);
        }

        if (j < NIT - 1) lds_barrier();
    }

    // ---- epilogue ----
    l += __shfl_xor(l, 32);        // combine the two hi-halves of column q=n
    float inv = 1.0f / l;
    float* orow = Op + (size_t)n * D_KV;
#pragma unroll
    for (int mg = 0; mg < 4; ++mg) {
        int d0 = 8 * mg + 4 * hi;
        float4 a = {o0[4 * mg] * inv, o0[4 * mg + 1] * inv,
                    o0[4 * mg + 2] * inv, o0[4 * mg + 3] * inv};
        float4 c = {o1[4 * mg] * inv, o1[4 * mg + 1] * inv,
                    o1[4 * mg + 2] * inv, o1[4 * mg + 3] * inv};
        *(float4*)(orow + d0)      = a;
        *(float4*)(orow + 32 + d0) = c;
    }
}

extern "C" void kernel_launch(void* const* d_in, const int* in_sizes, int n_in,
                              void* d_out, int out_size, void* d_ws, size_t ws_size,
                              hipStream_t stream) {
    const float* Q = (const float*)d_in[0];
    const float* K = (const float*)d_in[1];
    const float* V = (const float*)d_in[2];
    const float* M = (const float*)d_in[3];
    float*       O = (float*)d_out;
    dim3 grid(S_LEN / BQ, 32);   // 16 q-tiles x (B*H)=32
    attn_fwd<<<grid, 256, 0, stream>>>(Q, K, V, M, O);
}

// Round 7
// 203.715 us; speedup vs baseline: 1.3055x; 1.0038x over previous
//
#include <hip/hip_runtime.h>
#include <hip/hip_bf16.h>
#include <math.h>

#define S_LEN 2048
#define D_KV  64
#define BQ    128                  // 4 waves x 32 q-rows
#define BK    64
#define NIT   (S_LEN / BK)         // 32 key tiles
#define CHUNK 512                  // shorts per glds chunk (64 lanes x 8)
#define KTILE_SHORTS (8 * CHUNK)   // 4096 shorts = 8 KB per K (or V) tile
#define PREP_UNITS (32 * 32 * 4 * 2 * 64)   // 524288 16B-units per tensor

typedef __attribute__((ext_vector_type(8)))  short    bh8;    // 8 bf16
typedef __attribute__((ext_vector_type(4)))  unsigned ux4;
typedef __attribute__((ext_vector_type(16))) float    f32x16; // 32x32 C/D frag

__device__ __forceinline__ short f2bf(float f) {
    unsigned u = __builtin_bit_cast(unsigned, f);
    u += 0x7fffu + ((u >> 16) & 1u);   // RNE
    return (short)(u >> 16);
}
__device__ __forceinline__ unsigned pk2(float a, float b) {
    return (unsigned)(unsigned short)f2bf(a) |
           ((unsigned)(unsigned short)f2bf(b) << 16);
}
// async global->LDS DMA, 16 B/lane; LDS dest = uniform base + lane*16
__device__ __forceinline__ void glds16(const short* g, short* l) {
    __builtin_amdgcn_global_load_lds(
        (const __attribute__((address_space(1))) unsigned*)g,
        (__attribute__((address_space(3))) unsigned*)l, 16, 0, 0);
}

// ---- pre-pass: K fp32 -> bf16 in QK A-frag order ----
// unit g: lam=g&63 (n=lam&31,hi=lam>>5), q=(g>>6)&1, kc=(g>>7)&3, kt=(g>>9)&31, bh=g>>14
// content: lane lam of chunk(bh,kt,kc,q) = K[bh][kt*64+q*32+n][kc*16+hi*8 .. +8]
__global__ void prep_k(const float* __restrict__ K, short* __restrict__ Kf) {
    int g   = blockIdx.x * 256 + threadIdx.x;
    int lam = g & 63, n = lam & 31, hi = lam >> 5;
    int q   = (g >> 6) & 1;
    int kc  = (g >> 7) & 3;
    int kt  = (g >> 9) & 31;
    int bh  = g >> 14;
    const float* src = K + ((size_t)bh * S_LEN + kt * 64 + q * 32 + n) * D_KV
                         + kc * 16 + hi * 8;
    float4 a0 = *(const float4*)src;
    float4 a1 = *(const float4*)(src + 4);
    bh8 f;
    f[0] = f2bf(a0.x); f[1] = f2bf(a0.y); f[2] = f2bf(a0.z); f[3] = f2bf(a0.w);
    f[4] = f2bf(a1.x); f[5] = f2bf(a1.y); f[6] = f2bf(a1.z); f[7] = f2bf(a1.w);
    *(bh8*)(Kf + (size_t)g * 8) = f;
}

// ---- pre-pass: V fp32 -> bf16 in PV A-frag (V^T) order ----
// content: lane lam of chunk(bh,kt,kc,u) = V[bh][kt*64+kc*16+hi*8+e][u*32+n], e=0..7
__global__ void prep_v(const float* __restrict__ V, short* __restrict__ Vf) {
    int g   = blockIdx.x * 256 + threadIdx.x;
    int lam = g & 63, n = lam & 31, hi = lam >> 5;
    int u   = (g >> 6) & 1;
    int kc  = (g >> 7) & 3;
    int kt  = (g >> 9) & 31;
    int bh  = g >> 14;
    const float* src = V + ((size_t)bh * S_LEN + kt * 64 + kc * 16 + hi * 8) * D_KV
                         + u * 32 + n;
    bh8 f;
#pragma unroll
    for (int e = 0; e < 8; ++e) f[e] = f2bf(src[(size_t)e * D_KV]);
    *(bh8*)(Vf + (size_t)g * 8) = f;
}

__global__ __launch_bounds__(256, 2)
void attn_fwd(const float* __restrict__ Qg, const short* __restrict__ Kf,
              const short* __restrict__ Vf, const float* __restrict__ Mg,
              float* __restrict__ Og)
{
    // [pb][ K 4096 | V 4096 ] shorts = 32 KB, no padding (lane-linear frags)
    __shared__ __align__(16) short smem[2 * 2 * KTILE_SHORTS];

    const int tid  = threadIdx.x;
    const int wave = tid >> 6;
    const int lane = tid & 63;
    const int n    = lane & 31;
    const int hi   = lane >> 5;

    const int qt = blockIdx.x;
    const int bh = blockIdx.y;
    const int b  = bh >> 4;

    const int qw = qt * BQ + wave * 32;

    const float* Qp  = Qg + ((size_t)bh * S_LEN + qw) * D_KV;
    const short* Kfb = Kf + (size_t)bh * (NIT * KTILE_SHORTS);
    const short* Vfb = Vf + (size_t)bh * (NIT * KTILE_SHORTS);
    const float* Mp  = Mg + (size_t)b * S_LEN * S_LEN;
    float*       Op  = Og + ((size_t)bh * S_LEN + qw) * D_KV;

    // ---- Q^T B-frags: B[k=d=kc*16+hi*8+j][col=q=n], scale 1/8 folded (pow2) ----
    bh8 qf[4];
#pragma unroll
    for (int kc = 0; kc < 4; ++kc) {
        const float* src = Qp + n * D_KV + kc * 16 + hi * 8;
        float4 a0 = *(const float4*)(src);
        float4 a1 = *(const float4*)(src + 4);
        bh8 f;
        f[0] = f2bf(a0.x * 0.125f); f[1] = f2bf(a0.y * 0.125f);
        f[2] = f2bf(a0.z * 0.125f); f[3] = f2bf(a0.w * 0.125f);
        f[4] = f2bf(a1.x * 0.125f); f[5] = f2bf(a1.y * 0.125f);
        f[6] = f2bf(a1.z * 0.125f); f[7] = f2bf(a1.w * 0.125f);
        qf[kc] = f;
    }

    f32x16 o0, o1;
    float  l = 0.f;
#pragma unroll
    for (int i = 0; i < 16; ++i) { o0[i] = 0.f; o1[i] = 0.f; }

    float4 mreg[2][8];

    // stage tile kt into buffer pb: 4 glds per wave (2 K chunks + 2 V chunks)
    auto stage = [&](int kt, int pb) {
        const short* gk = Kfb + (size_t)kt * KTILE_SHORTS;
        const short* gv = Vfb + (size_t)kt * KTILE_SHORTS;
        short* lk = &smem[pb * 2 * KTILE_SHORTS];
        short* lv = lk + KTILE_SHORTS;
#pragma unroll
        for (int i = 0; i < 2; ++i) {
            int idx = wave + 4 * i;
            glds16(gk + idx * CHUNK + lane * 8, lk + idx * CHUNK);
            glds16(gv + idx * CHUNK + lane * 8, lv + idx * CHUNK);
        }
    };
    auto load_mask = [&](int kt, int mb) {
        const float* mrow = Mp + (size_t)(qw + n) * S_LEN + kt + 4 * hi;
#pragma unroll
        for (int mg = 0; mg < 4; ++mg) {
            mreg[mb][2 * mg]     = *(const float4*)(mrow + mg * 8);
            mreg[mb][2 * mg + 1] = *(const float4*)(mrow + 32 + mg * 8);
        }
    };

    auto body = [&](int j, int pb) {
        const short* lk = &smem[pb * 2 * KTILE_SHORTS];
        const short* lv = lk + KTILE_SHORTS;

        if (j + 1 < NIT) load_mask((j + 1) * BK, pb ^ 1);

        // ---- QK^T: T = K * Q^T, two 32x32 tiles ----
        f32x16 s0, s1;
#pragma unroll
        for (int i = 0; i < 16; ++i) { s0[i] = 0.f; s1[i] = 0.f; }
#pragma unroll
        for (int kc = 0; kc < 4; ++kc) {
            bh8 kf0 = *(const bh8*)&lk[(kc * 2 + 0) * CHUNK + lane * 8];
            bh8 kf1 = *(const bh8*)&lk[(kc * 2 + 1) * CHUNK + lane * 8];
            s0 = __builtin_amdgcn_mfma_f32_32x32x16_bf16(kf0, qf[kc], s0, 0, 0, 0);
            s1 = __builtin_amdgcn_mfma_f32_32x32x16_bf16(kf1, qf[kc], s1, 0, 0, 0);
        }

        // ---- mask + keep-positive + exp (fixed max 0) ----
        unsigned pk0[8], pk1[8];
#pragma unroll
        for (int mg = 0; mg < 4; ++mg) {
            float4 m0 = mreg[pb][2 * mg];
            float4 m1 = mreg[pb][2 * mg + 1];
            float ma[4] = {m0.x, m0.y, m0.z, m0.w};
            float mb4[4] = {m1.x, m1.y, m1.z, m1.w};
            float p0[4], p1[4];
#pragma unroll
            for (int x = 0; x < 4; ++x) {
                int r = 4 * mg + x;
                float t0 = s0[r] * ma[x];
                float t1 = s1[r] * mb4[x];
                p0[x] = (t0 > 0.f) ? __expf(t0) : 0.f;
                p1[x] = (t1 > 0.f) ? __expf(t1) : 0.f;
                l += p0[x] + p1[x];
            }
            pk0[2 * mg]     = pk2(p0[0], p0[1]);
            pk0[2 * mg + 1] = pk2(p0[2], p0[3]);
            pk1[2 * mg]     = pk2(p1[0], p1[1]);
            pk1[2 * mg + 1] = pk2(p1[2], p1[3]);
        }

        // ---- O^T += V^T * P^T : B-frag of P^T via one xor-32 exchange ----
#pragma unroll
        for (int kc = 0; kc < 4; ++kc) {
            const unsigned* pk = (kc < 2) ? pk0 : pk1;
            int kk = kc & 1;
            unsigned X0 = hi ? pk[4 * kk]     : pk[4 * kk + 2];
            unsigned X1 = hi ? pk[4 * kk + 1] : pk[4 * kk + 3];
            unsigned Y0 = (unsigned)__shfl_xor((int)X0, 32);
            unsigned Y1 = (unsigned)__shfl_xor((int)X1, 32);
            ux4 bb;
            if (hi) { bb[0] = Y0; bb[1] = Y1; bb[2] = pk[4 * kk + 2]; bb[3] = pk[4 * kk + 3]; }
            else    { bb[0] = pk[4 * kk]; bb[1] = pk[4 * kk + 1]; bb[2] = Y0; bb[3] = Y1; }
            bh8 pb8 = __builtin_bit_cast(bh8, bb);
            bh8 vf0 = *(const bh8*)&lv[(kc * 2 + 0) * CHUNK + lane * 8];
            bh8 vf1 = *(const bh8*)&lv[(kc * 2 + 1) * CHUNK + lane * 8];
            o0 = __builtin_amdgcn_mfma_f32_32x32x16_bf16(vf0, pb8, o0, 0, 0, 0);
            o1 = __builtin_amdgcn_mfma_f32_32x32x16_bf16(vf1, pb8, o1, 0, 0, 0);
        }

        __syncthreads();                       // tile j+1 glds drained (issued 1 iter ago)
        if (j + 2 < NIT) stage(j + 2, pb);     // all reads of buf pb done by all waves
    };

    // ---- prologue ----
    stage(0, 0);
    stage(1, 1);
    load_mask(0, 0);
    __syncthreads();

    for (int jj = 0; jj < NIT; jj += 2) {
        body(jj, 0);
        body(jj + 1, 1);
    }

    // ---- epilogue ----
    l += __shfl_xor(l, 32);
    float inv = 1.0f / l;
    float* orow = Op + (size_t)n * D_KV;
#pragma unroll
    for (int mg = 0; mg < 4; ++mg) {
        int d0 = 8 * mg + 4 * hi;
        float4 a = {o0[4 * mg] * inv, o0[4 * mg + 1] * inv,
                    o0[4 * mg + 2] * inv, o0[4 * mg + 3] * inv};
        float4 c = {o1[4 * mg] * inv, o1[4 * mg + 1] * inv,
                    o1[4 * mg + 2] * inv, o1[4 * mg + 3] * inv};
        *(float4*)(orow + d0)      = a;
        *(float4*)(orow + 32 + d0) = c;
    }
}

extern "C" void kernel_launch(void* const* d_in, const int* in_sizes, int n_in,
                              void* d_out, int out_size, void* d_ws, size_t ws_size,
                              hipStream_t stream) {
    const float* Q = (const float*)d_in[0];
    const float* K = (const float*)d_in[1];
    const float* V = (const float*)d_in[2];
    const float* M = (const float*)d_in[3];
    float*       O = (float*)d_out;

    short* Kf = (short*)d_ws;                       // 8 MB
    short* Vf = Kf + (size_t)PREP_UNITS * 8;        // 8 MB

    prep_k<<<PREP_UNITS / 256, 256, 0, stream>>>(K, Kf);
    prep_v<<<PREP_UNITS / 256, 256, 0, stream>>>(V, Vf);

    dim3 grid(S_LEN / BQ, 32);   // 16 q-tiles x (B*H)=32
    attn_fwd<<<grid, 256, 0, stream>>>(Q, Kf, Vf, M, O);
}